// Round 9
// baseline (1860.296 us; speedup 1.0000x reference)
//
#include <hip/hip_runtime.h>
#include <hip/hip_fp16.h>
#include <cstdint>
#include <cstddef>

#define B_   2048
#define T_   13
#define D0_  188
#define H_   256
#define G_   768   // 3*H
#define L_   8
#define DC_  512   // 2*H concat width
#define WFLD_ (8*48*64*8)   // halfs per (layer,dir) in fragment-packed W_hh = 196608

typedef _Float16 half8_ __attribute__((ext_vector_type(8)));
typedef float    f32x4_ __attribute__((ext_vector_type(4)));

__device__ __forceinline__ float sigmoidf_(float x){ return 1.f/(1.f + expf(-x)); }

// ---------------- fallback: zero d_out (diagnostic path if ws_size is tiny) ----------------
__global__ __launch_bounds__(256) void k_zero(float* __restrict__ o, int n){
  int i = blockIdx.x*256 + threadIdx.x;
  if (i < n) o[i] = 0.f;
}

// ---------------- pack W_hh [16][G][H] fp32 -> MFMA B-fragment layout fp16:
// WF[ld][kk(8)][c(48)][lane(64)][8], frag elem j: B[n=lane&15][k=(lane>>4)*8+j] of tile (c,kk)
__global__ __launch_bounds__(64) void k_pack_whh(const float* __restrict__ W,
                                                 __half* __restrict__ WF){
  int kk = blockIdx.x, c = blockIdx.y, ld = blockIdx.z;
  int lane = threadIdx.x, n = lane & 15, quad = lane >> 4;
  int col = c*16 + n;
  const float* src = W + ((size_t)ld*G_ + col)*H_ + kk*32 + quad*8;
  __half tmp[8];
#pragma unroll
  for (int j=0;j<8;j++) tmp[j] = __float2half(src[j]);
  *(uint4*)(WF + (size_t)ld*WFLD_ + (((size_t)kk*48 + c)*64 + lane)*8) = *(uint4*)tmp;
}

// ---------------- staging helpers: load 8 elems (guarded) -> 8 halfs ----------------
__device__ __forceinline__ void load8_(const float* s, int rem, __half* d){
  if (rem >= 8){
#pragma unroll
    for (int u=0;u<8;u++) d[u] = __float2half(s[u]);
  } else {
#pragma unroll
    for (int u=0;u<8;u++) d[u] = (u<rem) ? __float2half(s[u]) : __ushort_as_half((unsigned short)0);
  }
}
__device__ __forceinline__ void load8_(const __half* s, int rem, __half* d){
  if (rem >= 8){
    *(uint4*)d = *(const uint4*)s;
  } else {
#pragma unroll
    for (int u=0;u<8;u++) d[u] = (u<rem) ? s[u] : __ushort_as_half((unsigned short)0);
  }
}

// ---------------- gx GEMM via MFMA f16 (R6-proven, unchanged) ----------------
template<typename TIN>
__global__ __launch_bounds__(256) void k_gx_mfma(
    const TIN* __restrict__ inp,     // [C][T][Kmem]
    const float* __restrict__ Wi,    // [2][G][Kmem] fp32
    const float* __restrict__ bihL,  // [2][G] fp32
    __half* __restrict__ gx,         // [2][T][C][G] fp16
    int C, int Kmem, int Kpad)
{
  __shared__ __half As[128][40];
  __shared__ __half Bs[64][40];
  const int dir = blockIdx.z / T_, t = blockIdx.z % T_;
  const int b0 = blockIdx.x*128, g0 = blockIdx.y*64;
  const int tid = threadIdx.x;
  const int wave = tid>>6, lane = tid&63;
  const int quad = lane>>4, lr = lane&15;
  f32x4_ acc[2][4];
#pragma unroll
  for (int i=0;i<2;i++)
#pragma unroll
    for (int j=0;j<4;j++) acc[i][j] = (f32x4_){0.f,0.f,0.f,0.f};

  const int sr  = tid>>2;
  const int seg = (tid&3)*8;

  for (int k0=0;k0<Kpad;k0+=32){
    const int gk = k0 + seg;
#pragma unroll
    for (int p=0;p<2;p++){
      int r = sr + 64*p;
      __half tmp[8];
      load8_(&inp[((size_t)(b0+r)*T_ + t)*Kmem + gk], Kmem - gk, tmp);
      *(uint4*)&As[r][seg] = *(uint4*)tmp;
    }
    {
      __half tmp[8];
      load8_(&Wi[((size_t)dir*G_ + g0 + sr)*Kmem + gk], Kmem - gk, tmp);
      *(uint4*)&Bs[sr][seg] = *(uint4*)tmp;
    }
    __syncthreads();
    half8_ av[2], bv[4];
#pragma unroll
    for (int i=0;i<2;i++) av[i] = *(const half8_*)&As[wave*32 + i*16 + lr][quad*8];
#pragma unroll
    for (int j=0;j<4;j++) bv[j] = *(const half8_*)&Bs[j*16 + lr][quad*8];
#pragma unroll
    for (int i=0;i<2;i++)
#pragma unroll
      for (int j=0;j<4;j++)
        acc[i][j] = __builtin_amdgcn_mfma_f32_16x16x32_f16(av[i], bv[j], acc[i][j], 0, 0, 0);
    __syncthreads();
  }
  float bj[4];
#pragma unroll
  for (int j=0;j<4;j++) bj[j] = bihL[dir*G_ + g0 + j*16 + lr];
  const size_t obase = (size_t)(dir*T_ + t)*C*(size_t)G_;
#pragma unroll
  for (int i=0;i<2;i++){
#pragma unroll
    for (int r=0;r<4;r++){
      int row = b0 + wave*32 + i*16 + quad*4 + r;
#pragma unroll
      for (int j=0;j<4;j++){
        int col = g0 + j*16 + lr;
        gx[obase + (size_t)row*G_ + col] = __float2half(acc[i][j][r] + bj[j]);
      }
    }
  }
}

// ---------------- GRU recurrence via MFMA, weight-stationary registers.
// One block = 16 rows x 1 dir, 4 waves, __launch_bounds__(256,1) -> up to 512 VGPR/wave.
// Wave w owns ntiles c = w + 4m, m in [0,12): m<10 weights live in registers/AGPRs
// (loaded once per layer, zero per-step L2 traffic); m=10,11 streamed with dbuf.
// Per step: stream stage-0 loads -> deferred out-stores -> gx prefetch -> 8 MFMA stages
// -> gate math in registers -> barrier -> LDS h update -> barrier. Numerics identical to R8.
__global__ __launch_bounds__(256, 1) void k_gru_rec(
    const __half* __restrict__ gx,    // [2][T][C][G] fp16
    const __half* __restrict__ WFl,   // [2][8][48][64][8] fp16 (frag-packed)
    const float*  __restrict__ bhhL,  // [2][G] fp32
    __half* __restrict__ out,         // [C][T][DC] fp16; dir writes cols dir*H..dir*H+255
    float*  __restrict__ hsum,        // [2][C][H] fp32
    int init, int C)
{
  const int dir  = blockIdx.y;
  const int b0   = blockIdx.x * 16;
  const int tid  = threadIdx.x;
  const int wave = tid >> 6, lane = tid & 63;
  const int quad = lane >> 4, ln = lane & 15;

  __shared__ __half hsA[16][264];
  for (int i = tid; i < 16*264; i += 256) ((__half*)hsA)[i] = __ushort_as_half((unsigned short)0);

  float hreg[4][4];
#pragma unroll
  for (int i=0;i<4;i++)
#pragma unroll
    for (int r=0;r<4;r++) hreg[i][r] = 0.f;

  float bR[4], bZ[4], bN[4];
#pragma unroll
  for (int i=0;i<4;i++){
    int col = (wave + 4*i)*16 + ln;
    bR[i] = bhhL[dir*G_ + col];
    bZ[i] = bhhL[dir*G_ + H_  + col];
    bN[i] = bhhL[dir*G_ + 2*H_ + col];
  }

  const half8_* WF8 = (const half8_*)(WFl + (size_t)dir*WFLD_);

  // ---- prologue: weights for m=0..9 into registers (once per layer) ----
  half8_ wreg[10][8];
#pragma unroll
  for (int kk=0;kk<8;kk++)
#pragma unroll
    for (int m=0;m<10;m++)
      wreg[m][kk] = WF8[(size_t)(kk*48 + wave + 4*m)*64 + lane];

  __syncthreads();

  int ttprev = 0;
  for (int t=0;t<T_;t++){
    const int tt = dir ? (T_-1-t) : t;

    // ---- (1) streamed-tile stage-0 prefetch (m=10,11) ----
    half8_ bfn[2][2];
#pragma unroll
    for (int s=0;s<2;s++) bfn[0][s] = WF8[(size_t)(0*48 + wave + 4*(10+s))*64 + lane];

    // ---- (2) deferred out-store of previous step's h (retires under MFMA phase) ----
    if (t > 0){
#pragma unroll
      for (int i=0;i<4;i++){
        const int col = (wave + 4*i)*16 + ln;
#pragma unroll
        for (int r=0;r<4;r++){
          const int row = quad*4 + r;
          out[((size_t)(b0+row)*T_ + ttprev)*DC_ + dir*H_ + col] = __float2half(hreg[i][r]);
        }
      }
    }

    // ---- (3) gx prefetch for this step (h-independent) ----
    const __half* gxp = gx + ((size_t)(dir*T_ + tt)*C + b0)*G_;
    __half gxh[3][4][4];
#pragma unroll
    for (int i=0;i<4;i++){
      const int col = (wave + 4*i)*16 + ln;
#pragma unroll
      for (int r=0;r<4;r++){
        const __half* pb = gxp + (size_t)(quad*4+r)*G_ + col;
        gxh[0][i][r] = pb[0];
        gxh[1][i][r] = pb[H_];
        gxh[2][i][r] = pb[2*H_];
      }
    }

    // ---- (4) MFMA phase: 10 register tiles + 2 streamed tiles per stage ----
    f32x4_ acc[12];
#pragma unroll
    for (int m=0;m<12;m++) acc[m] = (f32x4_){0.f,0.f,0.f,0.f};
#pragma unroll
    for (int kk=0;kk<8;kk++){
      const int cur = kk & 1, nxt = cur ^ 1;
      if (kk < 7){
#pragma unroll
        for (int s=0;s<2;s++)
          bfn[nxt][s] = WF8[(size_t)((kk+1)*48 + wave + 4*(10+s))*64 + lane];
      }
      half8_ af = *(const half8_*)&hsA[ln][kk*32 + quad*8];
#pragma unroll
      for (int m=0;m<10;m++)
        acc[m] = __builtin_amdgcn_mfma_f32_16x16x32_f16(af, wreg[m][kk], acc[m], 0, 0, 0);
#pragma unroll
      for (int s=0;s<2;s++)
        acc[10+s] = __builtin_amdgcn_mfma_f32_16x16x32_f16(af, bfn[cur][s], acc[10+s], 0, 0, 0);
    }

    // ---- (5) gate phase: everything in registers ----
#pragma unroll
    for (int i=0;i<4;i++){
#pragma unroll
      for (int r=0;r<4;r++){
        float gr = __half2float(gxh[0][i][r]);
        float gz = __half2float(gxh[1][i][r]);
        float gn = __half2float(gxh[2][i][r]);
        float rr = sigmoidf_(gr + bR[i] + acc[i  ][r]);
        float zz = sigmoidf_(gz + bZ[i] + acc[i+4][r]);
        float nn = tanhf(gn + rr*(bN[i] + acc[i+8][r]));   // b_hn inside r* (PyTorch semantics)
        hreg[i][r] = (1.f - zz)*nn + zz*hreg[i][r];
      }
    }
    __syncthreads();   // all waves' A-frag reads of old h complete
#pragma unroll
    for (int i=0;i<4;i++){
      const int col = (wave + 4*i)*16 + ln;
#pragma unroll
      for (int r=0;r<4;r++)
        hsA[quad*4 + r][col] = __float2half(hreg[i][r]);
    }
    __syncthreads();   // new h visible before next step's A-frag reads
    ttprev = tt;
  }

  // ---- final step's out-store + hsum ----
#pragma unroll
  for (int i=0;i<4;i++){
    const int col = (wave + 4*i)*16 + ln;
#pragma unroll
    for (int r=0;r<4;r++){
      const int row = quad*4 + r;
      out[((size_t)(b0+row)*T_ + ttprev)*DC_ + dir*H_ + col] = __float2half(hreg[i][r]);
      float* dst = &hsum[((size_t)dir*C + b0 + row)*H_ + col];
      if (init) *dst = hreg[i][r]; else *dst += hreg[i][r];
    }
  }
}

// ---------------- head (per chunk) ----------------
__global__ __launch_bounds__(256) void k_head(
    const float* __restrict__ hsum, // [2][C][H]
    const float* __restrict__ W1, const float* __restrict__ b1,
    const float* __restrict__ W2, const float* __restrict__ b2,
    const float* __restrict__ Wc, const float* __restrict__ bc,
    float* __restrict__ outp, int C)
{
  __shared__ float hb[4][H_];
  __shared__ float y1[4][64];
  __shared__ float y2[4][32];
  int w = threadIdx.x >> 6, lane = threadIdx.x & 63;
  int b = blockIdx.x*4 + w;
  for (int i=lane;i<H_;i+=64){
    float s = hsum[(size_t)b*H_ + i] + hsum[((size_t)C + b)*H_ + i];
    hb[w][i] = s * (1.f/16.f);
  }
  __syncthreads();
  {
    float s = b1[lane];
#pragma unroll 8
    for (int k=0;k<H_;k++) s = fmaf(W1[lane*H_ + k], hb[w][k], s);
    y1[w][lane] = s * (1.f/(1.f+expf(-s)));
  }
  __syncthreads();
  if (lane < 32){
    float s = b2[lane];
#pragma unroll
    for (int k=0;k<64;k++) s = fmaf(W2[lane*64 + k], y1[w][k], s);
    y2[w][lane] = s * (1.f/(1.f+expf(-s)));
  }
  __syncthreads();
  if (lane == 0){
    float s = bc[0];
#pragma unroll
    for (int k=0;k<32;k++) s = fmaf(Wc[k], y2[w][k], s);
    outp[b] = s;
  }
}

static inline size_t al256(size_t x){ return (x + 255) & ~(size_t)255; }

extern "C" void kernel_launch(void* const* d_in, const int* in_sizes, int n_in,
                              void* d_out, int out_size, void* d_ws, size_t ws_size,
                              hipStream_t stream)
{
  const float* x    = (const float*)d_in[0];
  const float* Wih0 = (const float*)d_in[1];
  const float* WihR = (const float*)d_in[2];
  const float* Whh  = (const float*)d_in[3];
  const float* bih  = (const float*)d_in[4];
  const float* bhh  = (const float*)d_in[5];
  const float* W1p  = (const float*)d_in[6];
  const float* b1p  = (const float*)d_in[7];
  const float* W2p  = (const float*)d_in[8];
  const float* b2p  = (const float*)d_in[9];
  const float* Wcp  = (const float*)d_in[10];
  const float* bcp  = (const float*)d_in[11];
  float* outp = (float*)d_out;
  (void)in_sizes; (void)n_in;

  auto need = [](int nc) -> size_t {
    size_t c = B_ / nc;
    size_t s = 0;
    s += al256((size_t)2*T_*c*G_*sizeof(__half));   // gx
    s += al256((size_t)c*T_*DC_*sizeof(__half));    // buf
    s += al256((size_t)16*H_*G_*sizeof(__half));    // WF
    s += al256((size_t)2*c*H_*sizeof(float));       // hsum
    return s;
  };
  const int ncs[5] = {1,2,4,8,16};
  int NC = 16; bool fits = false;
  for (int i=0;i<5;i++){ if (need(ncs[i]) <= ws_size){ NC = ncs[i]; fits = true; break; } }

  if (!fits){
    k_zero<<<(out_size + 255)/256, 256, 0, stream>>>(outp, out_size);
    return;
  }

  const size_t C = B_ / NC;
  char* p = (char*)d_ws;
  __half* gx   = (__half*)p;  p += al256((size_t)2*T_*C*G_*sizeof(__half));
  __half* buf  = (__half*)p;  p += al256((size_t)C*T_*DC_*sizeof(__half));
  __half* WF   = (__half*)p;  p += al256((size_t)16*H_*G_*sizeof(__half));
  float*  hsum = (float*)p;   p += al256((size_t)2*C*H_*sizeof(float));

  k_pack_whh<<<dim3(8, 48, 16), 64, 0, stream>>>(Whh, WF);

  for (int cc=0; cc<NC; cc++){
    const size_t b0c = (size_t)cc * C;
    for (int l=0;l<L_;l++){
      const float* Wi = (l==0) ? Wih0 : (WihR + (size_t)(l-1)*2*G_*DC_);
      if (l==0){
        k_gx_mfma<float><<<dim3(C/128, G_/64, 2*T_), 256, 0, stream>>>(
            x + b0c*T_*D0_, Wi, bih + (size_t)l*2*G_, gx, (int)C, D0_, 192);
      } else {
        k_gx_mfma<__half><<<dim3(C/128, G_/64, 2*T_), 256, 0, stream>>>(
            buf, Wi, bih + (size_t)l*2*G_, gx, (int)C, DC_, DC_);
      }
      k_gru_rec<<<dim3(C/16, 2), 256, 0, stream>>>(
          gx, WF + (size_t)l*2*WFLD_, bhh + (size_t)l*2*G_, buf,
          hsum, (l==0) ? 1 : 0, (int)C);
    }
    k_head<<<dim3(C/4), 256, 0, stream>>>(hsum, W1p,b1p,W2p,b2p,Wcp,bcp,
                                          outp + b0c, (int)C);
  }
}

// Round 10
// 1420.160 us; speedup vs baseline: 1.3099x; 1.3099x over previous
//
#include <hip/hip_runtime.h>
#include <hip/hip_fp16.h>
#include <cstdint>
#include <cstddef>

#define B_   2048
#define T_   13
#define D0_  188
#define H_   256
#define G_   768   // 3*H
#define L_   8
#define DC_  512   // 2*H concat width
#define WFLD_ (8*48*64*8)   // halfs per (layer,dir) in fragment-packed W_hh = 196608

typedef _Float16 half8_ __attribute__((ext_vector_type(8)));
typedef float    f32x4_ __attribute__((ext_vector_type(4)));

__device__ __forceinline__ float sigmoidf_(float x){ return 1.f/(1.f + expf(-x)); }

// ---------------- fallback: zero d_out (diagnostic path if ws_size is tiny) ----------------
__global__ __launch_bounds__(256) void k_zero(float* __restrict__ o, int n){
  int i = blockIdx.x*256 + threadIdx.x;
  if (i < n) o[i] = 0.f;
}

// ---------------- pack W_hh [16][G][H] fp32 -> MFMA B-fragment layout fp16:
// WF[ld][kk(8)][c(48)][lane(64)][8], frag elem j: B[n=lane&15][k=(lane>>4)*8+j] of tile (c,kk)
__global__ __launch_bounds__(64) void k_pack_whh(const float* __restrict__ W,
                                                 __half* __restrict__ WF){
  int kk = blockIdx.x, c = blockIdx.y, ld = blockIdx.z;
  int lane = threadIdx.x, n = lane & 15, quad = lane >> 4;
  int col = c*16 + n;
  const float* src = W + ((size_t)ld*G_ + col)*H_ + kk*32 + quad*8;
  __half tmp[8];
#pragma unroll
  for (int j=0;j<8;j++) tmp[j] = __float2half(src[j]);
  *(uint4*)(WF + (size_t)ld*WFLD_ + (((size_t)kk*48 + c)*64 + lane)*8) = *(uint4*)tmp;
}

// ---------------- staging helpers: load 8 elems (guarded) -> 8 halfs ----------------
__device__ __forceinline__ void load8_(const float* s, int rem, __half* d){
  if (rem >= 8){
#pragma unroll
    for (int u=0;u<8;u++) d[u] = __float2half(s[u]);
  } else {
#pragma unroll
    for (int u=0;u<8;u++) d[u] = (u<rem) ? __float2half(s[u]) : __ushort_as_half((unsigned short)0);
  }
}
__device__ __forceinline__ void load8_(const __half* s, int rem, __half* d){
  if (rem >= 8){
    *(uint4*)d = *(const uint4*)s;
  } else {
#pragma unroll
    for (int u=0;u<8;u++) d[u] = (u<rem) ? s[u] : __ushort_as_half((unsigned short)0);
  }
}

// ---------------- gx GEMM via MFMA f16 (R6-proven, unchanged) ----------------
template<typename TIN>
__global__ __launch_bounds__(256) void k_gx_mfma(
    const TIN* __restrict__ inp,     // [C][T][Kmem]
    const float* __restrict__ Wi,    // [2][G][Kmem] fp32
    const float* __restrict__ bihL,  // [2][G] fp32
    __half* __restrict__ gx,         // [2][T][C][G] fp16
    int C, int Kmem, int Kpad)
{
  __shared__ __half As[128][40];
  __shared__ __half Bs[64][40];
  const int dir = blockIdx.z / T_, t = blockIdx.z % T_;
  const int b0 = blockIdx.x*128, g0 = blockIdx.y*64;
  const int tid = threadIdx.x;
  const int wave = tid>>6, lane = tid&63;
  const int quad = lane>>4, lr = lane&15;
  f32x4_ acc[2][4];
#pragma unroll
  for (int i=0;i<2;i++)
#pragma unroll
    for (int j=0;j<4;j++) acc[i][j] = (f32x4_){0.f,0.f,0.f,0.f};

  const int sr  = tid>>2;
  const int seg = (tid&3)*8;

  for (int k0=0;k0<Kpad;k0+=32){
    const int gk = k0 + seg;
#pragma unroll
    for (int p=0;p<2;p++){
      int r = sr + 64*p;
      __half tmp[8];
      load8_(&inp[((size_t)(b0+r)*T_ + t)*Kmem + gk], Kmem - gk, tmp);
      *(uint4*)&As[r][seg] = *(uint4*)tmp;
    }
    {
      __half tmp[8];
      load8_(&Wi[((size_t)dir*G_ + g0 + sr)*Kmem + gk], Kmem - gk, tmp);
      *(uint4*)&Bs[sr][seg] = *(uint4*)tmp;
    }
    __syncthreads();
    half8_ av[2], bv[4];
#pragma unroll
    for (int i=0;i<2;i++) av[i] = *(const half8_*)&As[wave*32 + i*16 + lr][quad*8];
#pragma unroll
    for (int j=0;j<4;j++) bv[j] = *(const half8_*)&Bs[j*16 + lr][quad*8];
#pragma unroll
    for (int i=0;i<2;i++)
#pragma unroll
      for (int j=0;j<4;j++)
        acc[i][j] = __builtin_amdgcn_mfma_f32_16x16x32_f16(av[i], bv[j], acc[i][j], 0, 0, 0);
    __syncthreads();
  }
  float bj[4];
#pragma unroll
  for (int j=0;j<4;j++) bj[j] = bihL[dir*G_ + g0 + j*16 + lr];
  const size_t obase = (size_t)(dir*T_ + t)*C*(size_t)G_;
#pragma unroll
  for (int i=0;i<2;i++){
#pragma unroll
    for (int r=0;r<4;r++){
      int row = b0 + wave*32 + i*16 + quad*4 + r;
#pragma unroll
      for (int j=0;j<4;j++){
        int col = g0 + j*16 + lr;
        gx[obase + (size_t)row*G_ + col] = __float2half(acc[i][j][r] + bj[j]);
      }
    }
  }
}

// ---------------- GRU recurrence via MFMA, 8-wave blocks + partial weight residency.
// One block = 16 rows x 1 dir, 512 threads (8 waves -> 2 waves/SIMD). Wave w owns
// ctiles c = w + 8m, m=0..5 (gate triples c,c+16,c+32 stay in-wave: m={i,2+i,4+i}).
// K-stages 0..4 of this wave's 6 ctiles live in 120 VGPRs (loaded once/layer, zero
// per-step L2 traffic); stages 5..7 stream with dbuf (144 KB/block/step vs R8's 384).
// Numerics identical to R8 -> absmax must remain 6.103516e-05.
__global__ __launch_bounds__(512, 2) void k_gru_rec(
    const __half* __restrict__ gx,    // [2][T][C][G] fp16
    const __half* __restrict__ WFl,   // [2][8][48][64][8] fp16 (frag-packed)
    const float*  __restrict__ bhhL,  // [2][G] fp32
    __half* __restrict__ out,         // [C][T][DC] fp16; dir writes cols dir*H..dir*H+255
    float*  __restrict__ hsum,        // [2][C][H] fp32
    int init, int C)
{
  const int dir  = blockIdx.y;
  const int b0   = blockIdx.x * 16;
  const int tid  = threadIdx.x;
  const int wave = tid >> 6, lane = tid & 63;
  const int quad = lane >> 4, ln = lane & 15;

  __shared__ __half hsA[16][264];
  for (int i = tid; i < 16*264; i += 512) ((__half*)hsA)[i] = __ushort_as_half((unsigned short)0);

  float hreg[2][4];
#pragma unroll
  for (int i=0;i<2;i++)
#pragma unroll
    for (int r=0;r<4;r++) hreg[i][r] = 0.f;

  float bR[2], bZ[2], bN[2];
#pragma unroll
  for (int i=0;i<2;i++){
    int col = (wave + 8*i)*16 + ln;
    bR[i] = bhhL[dir*G_ + col];
    bZ[i] = bhhL[dir*G_ + H_  + col];
    bN[i] = bhhL[dir*G_ + 2*H_ + col];
  }

  const half8_* WF8 = (const half8_*)(WFl + (size_t)dir*WFLD_);

  // ---- prologue: K-stages 0..4 of this wave's 6 ctiles -> registers (once per layer) ----
  half8_ wres[6][5];
#pragma unroll
  for (int kk=0;kk<5;kk++)
#pragma unroll
    for (int m=0;m<6;m++)
      wres[m][kk] = WF8[(size_t)(kk*48 + wave + 8*m)*64 + lane];

  __syncthreads();

  int ttprev = 0;
  for (int t=0;t<T_;t++){
    const int tt = dir ? (T_-1-t) : t;

    // ---- (1) streamed-stage prefetch: stage5 -> bf[0], stage6 -> bf[1] ----
    half8_ bf[2][6];
#pragma unroll
    for (int m=0;m<6;m++) bf[0][m] = WF8[(size_t)(5*48 + wave + 8*m)*64 + lane];
#pragma unroll
    for (int m=0;m<6;m++) bf[1][m] = WF8[(size_t)(6*48 + wave + 8*m)*64 + lane];

    // ---- (2) deferred out-store of previous step's h (retires under MFMA phase) ----
    if (t > 0){
#pragma unroll
      for (int i=0;i<2;i++){
        const int col = (wave + 8*i)*16 + ln;
#pragma unroll
        for (int r=0;r<4;r++){
          const int row = quad*4 + r;
          out[((size_t)(b0+row)*T_ + ttprev)*DC_ + dir*H_ + col] = __float2half(hreg[i][r]);
        }
      }
    }

    // ---- (3) gx prefetch for this step (h-independent) ----
    const __half* gxp = gx + ((size_t)(dir*T_ + tt)*C + b0)*G_;
    __half gxh[3][2][4];
#pragma unroll
    for (int i=0;i<2;i++){
      const int col = (wave + 8*i)*16 + ln;
#pragma unroll
      for (int r=0;r<4;r++){
        const __half* pb = gxp + (size_t)(quad*4+r)*G_ + col;
        gxh[0][i][r] = pb[0];
        gxh[1][i][r] = pb[H_];
        gxh[2][i][r] = pb[2*H_];
      }
    }

    // ---- (4) MFMA phase: stages 0..4 from registers (no waits), 5..7 streamed ----
    f32x4_ acc[6];
#pragma unroll
    for (int m=0;m<6;m++) acc[m] = (f32x4_){0.f,0.f,0.f,0.f};
#pragma unroll
    for (int kk=0;kk<5;kk++){
      half8_ af = *(const half8_*)&hsA[ln][kk*32 + quad*8];
#pragma unroll
      for (int m=0;m<6;m++)
        acc[m] = __builtin_amdgcn_mfma_f32_16x16x32_f16(af, wres[m][kk], acc[m], 0, 0, 0);
    }
    {
      half8_ af = *(const half8_*)&hsA[ln][5*32 + quad*8];
#pragma unroll
      for (int m=0;m<6;m++)
        acc[m] = __builtin_amdgcn_mfma_f32_16x16x32_f16(af, bf[0][m], acc[m], 0, 0, 0);
    }
#pragma unroll
    for (int m=0;m<6;m++)   // stage7 -> bf[0] (WAR after stage5 consumed)
      bf[0][m] = WF8[(size_t)(7*48 + wave + 8*m)*64 + lane];
    {
      half8_ af = *(const half8_*)&hsA[ln][6*32 + quad*8];
#pragma unroll
      for (int m=0;m<6;m++)
        acc[m] = __builtin_amdgcn_mfma_f32_16x16x32_f16(af, bf[1][m], acc[m], 0, 0, 0);
    }
    {
      half8_ af = *(const half8_*)&hsA[ln][7*32 + quad*8];
#pragma unroll
      for (int m=0;m<6;m++)
        acc[m] = __builtin_amdgcn_mfma_f32_16x16x32_f16(af, bf[0][m], acc[m], 0, 0, 0);
    }

    // ---- (5) gate phase: acc[i]=r, acc[2+i]=z, acc[4+i]=n ----
#pragma unroll
    for (int i=0;i<2;i++){
#pragma unroll
      for (int r=0;r<4;r++){
        float gr = __half2float(gxh[0][i][r]);
        float gz = __half2float(gxh[1][i][r]);
        float gn = __half2float(gxh[2][i][r]);
        float rr = sigmoidf_(gr + bR[i] + acc[i  ][r]);
        float zz = sigmoidf_(gz + bZ[i] + acc[2+i][r]);
        float nn = tanhf(gn + rr*(bN[i] + acc[4+i][r]));   // b_hn inside r* (PyTorch semantics)
        hreg[i][r] = (1.f - zz)*nn + zz*hreg[i][r];
      }
    }
    __syncthreads();   // all waves' A-frag reads of old h complete
#pragma unroll
    for (int i=0;i<2;i++){
      const int col = (wave + 8*i)*16 + ln;
#pragma unroll
      for (int r=0;r<4;r++)
        hsA[quad*4 + r][col] = __float2half(hreg[i][r]);
    }
    __syncthreads();   // new h visible before next step's A-frag reads
    ttprev = tt;
  }

  // ---- final step's out-store + hsum ----
#pragma unroll
  for (int i=0;i<2;i++){
    const int col = (wave + 8*i)*16 + ln;
#pragma unroll
    for (int r=0;r<4;r++){
      const int row = quad*4 + r;
      out[((size_t)(b0+row)*T_ + ttprev)*DC_ + dir*H_ + col] = __float2half(hreg[i][r]);
      float* dst = &hsum[((size_t)dir*C + b0 + row)*H_ + col];
      if (init) *dst = hreg[i][r]; else *dst += hreg[i][r];
    }
  }
}

// ---------------- head (per chunk) ----------------
__global__ __launch_bounds__(256) void k_head(
    const float* __restrict__ hsum, // [2][C][H]
    const float* __restrict__ W1, const float* __restrict__ b1,
    const float* __restrict__ W2, const float* __restrict__ b2,
    const float* __restrict__ Wc, const float* __restrict__ bc,
    float* __restrict__ outp, int C)
{
  __shared__ float hb[4][H_];
  __shared__ float y1[4][64];
  __shared__ float y2[4][32];
  int w = threadIdx.x >> 6, lane = threadIdx.x & 63;
  int b = blockIdx.x*4 + w;
  for (int i=lane;i<H_;i+=64){
    float s = hsum[(size_t)b*H_ + i] + hsum[((size_t)C + b)*H_ + i];
    hb[w][i] = s * (1.f/16.f);
  }
  __syncthreads();
  {
    float s = b1[lane];
#pragma unroll 8
    for (int k=0;k<H_;k++) s = fmaf(W1[lane*H_ + k], hb[w][k], s);
    y1[w][lane] = s * (1.f/(1.f+expf(-s)));
  }
  __syncthreads();
  if (lane < 32){
    float s = b2[lane];
#pragma unroll
    for (int k=0;k<64;k++) s = fmaf(W2[lane*64 + k], y1[w][k], s);
    y2[w][lane] = s * (1.f/(1.f+expf(-s)));
  }
  __syncthreads();
  if (lane == 0){
    float s = bc[0];
#pragma unroll
    for (int k=0;k<32;k++) s = fmaf(Wc[k], y2[w][k], s);
    outp[b] = s;
  }
}

static inline size_t al256(size_t x){ return (x + 255) & ~(size_t)255; }

extern "C" void kernel_launch(void* const* d_in, const int* in_sizes, int n_in,
                              void* d_out, int out_size, void* d_ws, size_t ws_size,
                              hipStream_t stream)
{
  const float* x    = (const float*)d_in[0];
  const float* Wih0 = (const float*)d_in[1];
  const float* WihR = (const float*)d_in[2];
  const float* Whh  = (const float*)d_in[3];
  const float* bih  = (const float*)d_in[4];
  const float* bhh  = (const float*)d_in[5];
  const float* W1p  = (const float*)d_in[6];
  const float* b1p  = (const float*)d_in[7];
  const float* W2p  = (const float*)d_in[8];
  const float* b2p  = (const float*)d_in[9];
  const float* Wcp  = (const float*)d_in[10];
  const float* bcp  = (const float*)d_in[11];
  float* outp = (float*)d_out;
  (void)in_sizes; (void)n_in;

  auto need = [](int nc) -> size_t {
    size_t c = B_ / nc;
    size_t s = 0;
    s += al256((size_t)2*T_*c*G_*sizeof(__half));   // gx
    s += al256((size_t)c*T_*DC_*sizeof(__half));    // buf
    s += al256((size_t)16*H_*G_*sizeof(__half));    // WF
    s += al256((size_t)2*c*H_*sizeof(float));       // hsum
    return s;
  };
  const int ncs[5] = {1,2,4,8,16};
  int NC = 16; bool fits = false;
  for (int i=0;i<5;i++){ if (need(ncs[i]) <= ws_size){ NC = ncs[i]; fits = true; break; } }

  if (!fits){
    k_zero<<<(out_size + 255)/256, 256, 0, stream>>>(outp, out_size);
    return;
  }

  const size_t C = B_ / NC;
  char* p = (char*)d_ws;
  __half* gx   = (__half*)p;  p += al256((size_t)2*T_*C*G_*sizeof(__half));
  __half* buf  = (__half*)p;  p += al256((size_t)C*T_*DC_*sizeof(__half));
  __half* WF   = (__half*)p;  p += al256((size_t)16*H_*G_*sizeof(__half));
  float*  hsum = (float*)p;   p += al256((size_t)2*C*H_*sizeof(float));

  k_pack_whh<<<dim3(8, 48, 16), 64, 0, stream>>>(Whh, WF);

  for (int cc=0; cc<NC; cc++){
    const size_t b0c = (size_t)cc * C;
    for (int l=0;l<L_;l++){
      const float* Wi = (l==0) ? Wih0 : (WihR + (size_t)(l-1)*2*G_*DC_);
      if (l==0){
        k_gx_mfma<float><<<dim3(C/128, G_/64, 2*T_), 256, 0, stream>>>(
            x + b0c*T_*D0_, Wi, bih + (size_t)l*2*G_, gx, (int)C, D0_, 192);
      } else {
        k_gx_mfma<__half><<<dim3(C/128, G_/64, 2*T_), 256, 0, stream>>>(
            buf, Wi, bih + (size_t)l*2*G_, gx, (int)C, DC_, DC_);
      }
      k_gru_rec<<<dim3(C/16, 2), 512, 0, stream>>>(
          gx, WF + (size_t)l*2*WFLD_, bhh + (size_t)l*2*G_, buf,
          hsum, (l==0) ? 1 : 0, (int)C);
    }
    k_head<<<dim3(C/4), 256, 0, stream>>>(hsum, W1p,b1p,W2p,b2p,Wcp,bcp,
                                          outp + b0c, (int)C);
  }
}